// Round 7
// baseline (58850.732 us; speedup 1.0000x reference)
//
#include <hip/hip_runtime.h>
#include <math.h>

#define BB 64
#define RR 1024
#define TT 200
#define HH 512
#define VV 1000
#define GG 2048
#define NBLK 256
#define NTHR 256

typedef float vf4 __attribute__((ext_vector_type(4)));

__device__ __forceinline__ float sigmf(float x) { return 1.f / (1.f + __expf(-x)); }

// coherent scalar access (agent scope = MALL): for cross-block data inside a phase
__device__ __forceinline__ void cstore(float* p, float v) {
  __hip_atomic_store(p, v, __ATOMIC_RELAXED, __HIP_MEMORY_SCOPE_AGENT);
}
__device__ __forceinline__ float cload(const float* p) {
  return __hip_atomic_load(p, __ATOMIC_RELAXED, __HIP_MEMORY_SCOPE_AGENT);
}
__device__ __forceinline__ int armw(int* p, int v) {
  return __hip_atomic_fetch_add(p, v, __ATOMIC_RELAXED, __HIP_MEMORY_SCOPE_AGENT);
}

// ---------------- transpose: dst[n][m] = src[m*sstride + soff + n] ----------------
__global__ __launch_bounds__(256) void transpose_k(const float* __restrict__ src,
    float* __restrict__ dst, int Msrc, int Mdst, int N, int sstride, int soff) {
  __shared__ float tile[32][33];
  int mt = blockIdx.y * 32, ntb = blockIdx.x * 32;
  int tx = threadIdx.x & 31, ty = threadIdx.x >> 5;
  #pragma unroll
  for (int i = ty; i < 32; i += 8) {
    int m = mt + i, n = ntb + tx;
    tile[i][tx] = (m < Msrc && n < N) ? src[(size_t)m * sstride + soff + n] : 0.f;
  }
  __syncthreads();
  #pragma unroll
  for (int i = ty; i < 32; i += 8) {
    int n = ntb + i, m = mt + tx;
    if (n < N && m < Mdst) dst[(size_t)n * Mdst + m] = tile[tx][i];
  }
}

// ---------------- big GEMM: C[M][cld] = A[M][512] @ W[512][wld-slab] + bias ----------------
__global__ __launch_bounds__(256) void biggemm_k(const float* __restrict__ A,
    const float* __restrict__ W, int wld, const float* __restrict__ bias,
    float* __restrict__ C, int cld, int Nout) {
  int mt = blockIdx.x * 128, ntile = blockIdx.y * 128;
  __shared__ float As[16][132];
  __shared__ float Ws[16][132];
  int tid = threadIdx.x;
  int ty = tid >> 4, tx = tid & 15;
  float acc[8][8] = {};
  for (int k0 = 0; k0 < 512; k0 += 16) {
    {
      int row = tid >> 1, kc = (tid & 1) * 8;
      float4 a0 = *(const float4*)&A[(size_t)(mt + row) * 512 + k0 + kc];
      float4 a1 = *(const float4*)&A[(size_t)(mt + row) * 512 + k0 + kc + 4];
      As[kc + 0][row] = a0.x; As[kc + 1][row] = a0.y; As[kc + 2][row] = a0.z; As[kc + 3][row] = a0.w;
      As[kc + 4][row] = a1.x; As[kc + 5][row] = a1.y; As[kc + 6][row] = a1.z; As[kc + 7][row] = a1.w;
      int krow = tid >> 4, nc = (tid & 15) * 8;
      *(float4*)&Ws[krow][nc]     = *(const float4*)&W[(size_t)(k0 + krow) * wld + ntile + nc];
      *(float4*)&Ws[krow][nc + 4] = *(const float4*)&W[(size_t)(k0 + krow) * wld + ntile + nc + 4];
    }
    __syncthreads();
    #pragma unroll
    for (int kk = 0; kk < 16; kk++) {
      float4 a0 = *(float4*)&As[kk][ty * 8];
      float4 a1 = *(float4*)&As[kk][ty * 8 + 4];
      float4 w0 = *(float4*)&Ws[kk][tx * 8];
      float4 w1 = *(float4*)&Ws[kk][tx * 8 + 4];
      float av[8] = {a0.x, a0.y, a0.z, a0.w, a1.x, a1.y, a1.z, a1.w};
      float wv[8] = {w0.x, w0.y, w0.z, w0.w, w1.x, w1.y, w1.z, w1.w};
      #pragma unroll
      for (int i = 0; i < 8; i++)
        #pragma unroll
        for (int j = 0; j < 8; j++)
          acc[i][j] += av[i] * wv[j];
    }
    __syncthreads();
  }
  #pragma unroll
  for (int i = 0; i < 8; i++) {
    int m = mt + ty * 8 + i;
    #pragma unroll
    for (int j = 0; j < 8; j++) {
      int n = ntile + tx * 8 + j;
      if (n < Nout) C[(size_t)m * cld + n] = acc[i][j] + bias[n];
    }
  }
}

// ---------------- tiny setup kernels ----------------
__global__ __launch_bounds__(256) void biasq_k(const float* __restrict__ psi_w,
    const float* __restrict__ phi_b, float* __restrict__ biasq) {
  int i = blockIdx.x * 256 + threadIdx.x;
  float v = 0.f;
  for (int k = 0; k < 512; k++) v += psi_w[(size_t)k * 512 + i] * phi_b[k];
  biasq[i] = v;
}
__global__ __launch_bounds__(256) void pb_k(const float* __restrict__ psi_b,
    const float* __restrict__ wc0T, float* __restrict__ pb) {
  int n = blockIdx.x * 256 + threadIdx.x;
  float v = 0.f;
  for (int k = 0; k < 512; k++) v += psi_b[k] * wc0T[(size_t)k * 2048 + n];
  pb[n] = v;
}

// ================= persistent loop kernel =================
struct SmGemm { float Ask[64][68]; float Wsk[64][68]; };
struct SmAttn { float qs[HH]; float wacc[4][HH]; float wml[8]; int cflag; };

// hierarchical grid barrier: 16 groups x 16 blocks; RMW-poll; leader-only fences. (R5-proven)
__device__ __forceinline__ void gbar(int* bar, int k1) {
  __syncthreads();
  if (threadIdx.x == 0) {
    __threadfence();                                  // release
    int g = blockIdx.x >> 4;
    int old = armw(&bar[g * 32], 1);
    if ((old & 15) == 15) {
      int o2 = armw(&bar[512], 1);
      if ((o2 & 15) == 15)
        __hip_atomic_store(&bar[544], k1, __ATOMIC_RELAXED, __HIP_MEMORY_SCOPE_AGENT);
    }
    if ((blockIdx.x & 15) == 0) {
      while (armw(&bar[544], 0) < k1) __builtin_amdgcn_s_sleep(1);
      __hip_atomic_store(&bar[576 + g * 32], k1, __ATOMIC_RELAXED, __HIP_MEMORY_SCOPE_AGENT);
    } else {
      while (armw(&bar[576 + g * 32], 0) < k1) __builtin_amdgcn_s_sleep(1);
    }
    __threadfence();                                  // acquire
  }
  __syncthreads();
}

// 64x64 output tile, K=128 starting at k0. A rows stride 512. (R5-proven)
__device__ __forceinline__ void sgemm_tile(const float* A, const float* W, int wld, int k0,
                                           float* Cout, int N, int nt, SmGemm* sm) {
  int tid = threadIdx.x;
  int b0 = (tid >> 4) * 4, n0 = (tid & 15) * 4;
  float acc[4][4] = {};
  for (int kb = 0; kb < 128; kb += 64) {
    {
      int brow = tid & 63;
      int kcb = (tid >> 6) * 16;
      const float* ap = A + (size_t)brow * 512 + k0 + kb + kcb;
      #pragma unroll
      for (int j = 0; j < 4; j++) {
        float4 a4 = *(const float4*)(ap + j * 4);
        sm->Ask[kcb + j * 4 + 0][brow] = a4.x;
        sm->Ask[kcb + j * 4 + 1][brow] = a4.y;
        sm->Ask[kcb + j * 4 + 2][brow] = a4.z;
        sm->Ask[kcb + j * 4 + 3][brow] = a4.w;
      }
      int nc = (tid & 15) * 4;
      #pragma unroll
      for (int j = 0; j < 4; j++) {
        int krow = (tid >> 4) + j * 16;
        *(float4*)&sm->Wsk[krow][nc] =
            *(const float4*)&W[(size_t)(k0 + kb + krow) * wld + nt * 64 + nc];
      }
    }
    __syncthreads();
    #pragma unroll
    for (int kk = 0; kk < 64; kk++) {
      float4 a = *(float4*)&sm->Ask[kk][b0];
      float4 w = *(float4*)&sm->Wsk[kk][n0];
      acc[0][0] += a.x * w.x; acc[0][1] += a.x * w.y; acc[0][2] += a.x * w.z; acc[0][3] += a.x * w.w;
      acc[1][0] += a.y * w.x; acc[1][1] += a.y * w.y; acc[1][2] += a.y * w.z; acc[1][3] += a.y * w.w;
      acc[2][0] += a.z * w.x; acc[2][1] += a.z * w.y; acc[2][2] += a.z * w.z; acc[2][3] += a.z * w.w;
      acc[3][0] += a.w * w.x; acc[3][1] += a.w * w.y; acc[3][2] += a.w * w.z; acc[3][3] += a.w * w.w;
    }
    __syncthreads();
  }
  float* C2 = Cout + (size_t)nt * 64;
  #pragma unroll
  for (int i = 0; i < 4; i++) {
    float4 v = make_float4(acc[i][0], acc[i][1], acc[i][2], acc[i][3]);
    *(float4*)&C2[(size_t)(b0 + i) * N + n0] = v;
  }
}

// attention with inline q: tile = b*4+ch, chunk = 256 rows, wave = 64 rows.
__device__ __forceinline__ void attn_tile(int tile, int t, const float* h,
    const float* s1, const float* Mt, const float* biasq,
    float* partm, float* partl, float* partacc, float* cbuf,
    int* bcnt, SmAttn* sm) {
  int tid = threadIdx.x;
  int b = tile >> 2, ch = tile & 3;
  // stage s1 row, then q = biasq + s1row @ Mt  (each thread: outputs d=tid, d=tid+256)
  for (int d = tid; d < HH; d += NTHR) sm->wacc[0][d] = s1[(size_t)b * HH + d];
  __syncthreads();
  {
    float a0 = biasq[tid], a1 = biasq[tid + 256];
    #pragma unroll 8
    for (int k = 0; k < 512; k++) {
      float sv = sm->wacc[0][k];
      a0 += sv * Mt[(size_t)k * 512 + tid];
      a1 += sv * Mt[(size_t)k * 512 + tid + 256];
    }
    sm->qs[tid] = a0; sm->qs[tid + 256] = a1;
  }
  __syncthreads();
  int wave = tid >> 6, lane = tid & 63;
  float qreg[8];
  {
    const float* qp = sm->qs + lane * 8;
    #pragma unroll
    for (int j = 0; j < 8; j++) qreg[j] = qp[j];
  }
  float m = -INFINITY, l = 0.f;
  float acc[8] = {};
  const vf4* hb = (const vf4*)(h + ((size_t)b * RR + ch * 256 + wave * 64) * HH) + lane * 2;
  vf4 a0 = __builtin_nontemporal_load(hb);
  vf4 a1 = __builtin_nontemporal_load(hb + 1);
  vf4 c0 = __builtin_nontemporal_load(hb + 128);
  vf4 c1 = __builtin_nontemporal_load(hb + 129);
  for (int i = 0; i < 64; i++) {
    vf4 n0v, n1v;
    if (i < 62) {
      n0v = __builtin_nontemporal_load(hb + (size_t)(i + 2) * 128);
      n1v = __builtin_nontemporal_load(hb + (size_t)(i + 2) * 128 + 1);
    }
    float rv[8] = {a0.x, a0.y, a0.z, a0.w, a1.x, a1.y, a1.z, a1.w};
    float d0 = 0.f;
    #pragma unroll
    for (int j = 0; j < 8; j++) d0 += qreg[j] * rv[j];
    #pragma unroll
    for (int off = 32; off > 0; off >>= 1) d0 += __shfl_xor(d0, off, 64);
    float mn = fmaxf(m, d0);
    float scl = __expf(m - mn);
    float w = __expf(d0 - mn);
    l = l * scl + w;
    #pragma unroll
    for (int j = 0; j < 8; j++) acc[j] = acc[j] * scl + w * rv[j];
    m = mn;
    a0 = c0; a1 = c1; c0 = n0v; c1 = n1v;
  }
  #pragma unroll
  for (int j = 0; j < 8; j++) sm->wacc[wave][lane * 8 + j] = acc[j];
  if (lane == 0) { sm->wml[wave] = m; sm->wml[4 + wave] = l; }
  __syncthreads();
  float M = fmaxf(fmaxf(sm->wml[0], sm->wml[1]), fmaxf(sm->wml[2], sm->wml[3]));
  float e0 = __expf(sm->wml[0] - M), e1 = __expf(sm->wml[1] - M);
  float e2 = __expf(sm->wml[2] - M), e3 = __expf(sm->wml[3] - M);
  if (tid == 0) {
    cstore(&partm[b * 4 + ch], M);
    cstore(&partl[b * 4 + ch], sm->wml[4] * e0 + sm->wml[5] * e1 + sm->wml[6] * e2 + sm->wml[7] * e3);
  }
  for (int d = tid; d < HH; d += NTHR)
    cstore(&partacc[((size_t)b * 4 + ch) * HH + d],
           sm->wacc[0][d] * e0 + sm->wacc[1][d] * e1 + sm->wacc[2][d] * e2 + sm->wacc[3][d] * e3);
  // gating: 4th finisher for batch b combines (order-independent math)
  __syncthreads();                       // drains all waves' stores (vmcnt)
  if (tid == 0) sm->cflag = armw(&bcnt[b], 1);
  __syncthreads();
  if (sm->cflag == 4 * t + 3) {
    float Mx = -INFINITY;
    #pragma unroll
    for (int p = 0; p < 4; p++) Mx = fmaxf(Mx, cload(&partm[b * 4 + p]));
    float sc2[4]; float L = 0.f;
    #pragma unroll
    for (int p = 0; p < 4; p++) {
      sc2[p] = __expf(cload(&partm[b * 4 + p]) - Mx);
      L += sc2[p] * cload(&partl[b * 4 + p]);
    }
    float inv = 1.f / L;
    for (int d = tid; d < HH; d += NTHR) {
      float v = 0.f;
      #pragma unroll
      for (int p = 0; p < 4; p++) v += sc2[p] * cload(&partacc[((size_t)b * 4 + p) * HH + d]);
      cbuf[b * HH + d] = v * inv;        // normal store; consumed after fenced barrier
    }
  }
}

__global__ __launch_bounds__(NTHR) void loop_k(
    const float* h, const float* Mt, const float* whh0T, const float* whh1T,
    const float* wih1T, const float* Bm, const float* wyT,
    const float* biasq, const float* pb,
    const float* b_ih0, const float* b_hh0,
    const float* b_ih1, const float* b_hh1, const int* y,
    float* s0, float* cs0, float* s1, float* cs1,
    float* g0part, float* g1part,
    float* partm, float* partl, float* partacc, float* cbuf, float* s_seq,
    int* bar, int* bcnt) {
  __shared__ __align__(16) char smraw[sizeof(SmGemm)];
  SmGemm* smg = (SmGemm*)smraw;
  SmAttn* sma = (SmAttn*)smraw;
  int bid = blockIdx.x, tid = threadIdx.x;
  int bk = 0;
  for (int t = 0; t < TT; t++) {
    // Phase A: attn (inline q, gated combine) + g0h (s0@whh0, tiles 0-127) + g1h (s1@whh1, 128-255)
    attn_tile(bid, t, h, s1, Mt, biasq, partm, partl, partacc, cbuf, bcnt, sma);
    __syncthreads();                     // LDS handoff: SmAttn -> SmGemm (cflag overlap)
    {
      int nt = bid & 31, kc = (bid >> 5) & 3;
      if (bid < 128)
        sgemm_tile(s0, whh0T, GG, kc * 128, g0part + (size_t)(4 + kc) * BB * GG, GG, nt, smg);
      else
        sgemm_tile(s1, whh1T, GG, kc * 128, g1part + (size_t)(4 + kc) * BB * GG, GG, nt, smg);
    }
    gbar(bar, ++bk);
    // Phase B: capp @ Bm -> g0part slabs 0-3
    if (bid < 128) {
      int nt = bid & 31, kc = bid >> 5;
      sgemm_tile(cbuf, Bm, GG, kc * 128, g0part + (size_t)kc * BB * GG, GG, nt, smg);
    }
    gbar(bar, ++bk);
    // Phase C: act0 -> s0, cs0
    {
      int idx = bid * NTHR + tid;
      if (idx < BB * HH) {
        int b = idx >> 9, jj = idx & 511;
        int yv = y[b * TT + t];
        float g[4];
        #pragma unroll
        for (int gi = 0; gi < 4; gi++) {
          int j = gi * 512 + jj;
          float v = b_ih0[j] + b_hh0[j] + pb[j] + wyT[(size_t)yv * GG + j];
          #pragma unroll
          for (int p = 0; p < 8; p++) v += g0part[((size_t)p * BB + b) * GG + j];
          g[gi] = v;
        }
        float cn = sigmf(g[1]) * cs0[idx] + sigmf(g[0]) * tanhf(g[2]);
        cs0[idx] = cn;
        s0[idx] = sigmf(g[3]) * tanhf(cn);
      }
    }
    gbar(bar, ++bk);
    // Phase D: s0 @ wih1 -> g1part slabs 0-3
    if (bid < 128) {
      int nt = bid & 31, kc = bid >> 5;
      sgemm_tile(s0, wih1T, GG, kc * 128, g1part + (size_t)kc * BB * GG, GG, nt, smg);
    }
    gbar(bar, ++bk);
    // Phase E: act1 -> s1, cs1, s_seq (NT store: keep h L3-resident)
    {
      int idx = bid * NTHR + tid;
      if (idx < BB * HH) {
        int b = idx >> 9, jj = idx & 511;
        float g[4];
        #pragma unroll
        for (int gi = 0; gi < 4; gi++) {
          int j = gi * 512 + jj;
          float v = b_ih1[j] + b_hh1[j];
          #pragma unroll
          for (int p = 0; p < 8; p++) v += g1part[((size_t)p * BB + b) * GG + j];
          g[gi] = v;
        }
        float cn = sigmf(g[1]) * cs1[idx] + sigmf(g[0]) * tanhf(g[2]);
        cs1[idx] = cn;
        float hv = sigmf(g[3]) * tanhf(cn);
        s1[idx] = hv;
        __builtin_nontemporal_store(hv, &s_seq[((size_t)b * TT + t) * HH + jj]);
      }
    }
    gbar(bar, ++bk);
  }
}

extern "C" void kernel_launch(void* const* d_in, const int* in_sizes, int n_in,
                              void* d_out, int out_size, void* d_ws, size_t ws_size,
                              hipStream_t stream) {
  (void)in_sizes; (void)n_in; (void)out_size; (void)ws_size;
  const float* h     = (const float*)d_in[0];
  const int*   y     = (const int*)d_in[1];
  const float* phi_w = (const float*)d_in[2];
  const float* phi_b = (const float*)d_in[3];
  const float* psi_w = (const float*)d_in[4];
  const float* psi_b = (const float*)d_in[5];
  const float* w_ih0 = (const float*)d_in[6];
  const float* w_hh0 = (const float*)d_in[7];
  const float* b_ih0 = (const float*)d_in[8];
  const float* b_hh0 = (const float*)d_in[9];
  const float* w_ih1 = (const float*)d_in[10];
  const float* w_hh1 = (const float*)d_in[11];
  const float* b_ih1 = (const float*)d_in[12];
  const float* b_hh1 = (const float*)d_in[13];
  const float* out_w = (const float*)d_in[14];
  const float* out_b = (const float*)d_in[15];
  float* out = (float*)d_out;

  float* ws = (float*)d_ws;
  size_t off = 0;
  auto alloc = [&](size_t n) { size_t o = off; off += (n + 63) & ~(size_t)63; return o; };
  float* barf   = ws + alloc(1216);                   // bar ints [0..1151] | bcnt [1152..1215]
  float* st     = ws + alloc(4 * BB * HH);
  float* psi_wT = ws + alloc(HH * HH);
  float* phi_wT = ws + alloc(HH * HH);
  float* Mt     = ws + alloc(HH * HH);
  float* wc0T   = ws + alloc(HH * GG);
  float* Bm     = ws + alloc(HH * GG);
  float* whh0T  = ws + alloc(HH * GG);
  float* wih1T  = ws + alloc(HH * GG);
  float* whh1T  = ws + alloc(HH * GG);
  float* wyT    = ws + alloc((size_t)VV * GG);
  float* out_wT = ws + alloc((size_t)HH * 1024);
  float* biasq  = ws + alloc(HH);
  float* pb     = ws + alloc(GG);
  float* zeros  = ws + alloc(GG);
  float* s0 = st, *cs0 = st + BB * HH, *s1 = st + 2 * BB * HH, *cs1 = st + 3 * BB * HH;
  float* cbuf   = ws + alloc(BB * HH);
  float* g0part = ws + alloc((size_t)8 * BB * GG);
  float* g1part = ws + alloc((size_t)8 * BB * GG);
  float* partm  = ws + alloc(BB * 4);
  float* partl  = ws + alloc(BB * 4);
  float* partacc= ws + alloc((size_t)BB * 4 * HH);
  float* s_seq  = ws + alloc((size_t)BB * TT * HH);

  int* bar  = (int*)barf;
  int* bcnt = (int*)barf + 1152;

  hipMemsetAsync(barf, 0, (1216 + (size_t)4 * BB * HH) * sizeof(float), stream);
  hipMemsetAsync(zeros, 0, GG * sizeof(float), stream);

  dim3 tb(256);
  transpose_k<<<dim3(16, 16), tb, 0, stream>>>(psi_w, psi_wT, 512, 512, 512, 512, 0);
  transpose_k<<<dim3(16, 16), tb, 0, stream>>>(phi_w, phi_wT, 512, 512, 512, 512, 0);
  transpose_k<<<dim3(16, 64), tb, 0, stream>>>(w_ih0, wc0T, 2048, 2048, 512, 1512, 1000);
  transpose_k<<<dim3(16, 64), tb, 0, stream>>>(w_hh0, whh0T, 2048, 2048, 512, 512, 0);
  transpose_k<<<dim3(16, 64), tb, 0, stream>>>(w_ih1, wih1T, 2048, 2048, 512, 512, 0);
  transpose_k<<<dim3(16, 64), tb, 0, stream>>>(w_hh1, whh1T, 2048, 2048, 512, 512, 0);
  transpose_k<<<dim3(32, 64), tb, 0, stream>>>(w_ih0, wyT, 2048, 2048, 1000, 1512, 0);
  transpose_k<<<dim3(16, 32), tb, 0, stream>>>(out_w, out_wT, 1000, 1024, 512, 512, 0);

  // Mt = phi_w^T @ psi_w ; Bm = psi_wT @ wc0T ; bias folds
  biggemm_k<<<dim3(4, 4), tb, 0, stream>>>(phi_wT, psi_w, 512, zeros, Mt, 512, 512);
  biggemm_k<<<dim3(4, 16), tb, 0, stream>>>(psi_wT, wc0T, 2048, zeros, Bm, 2048, 2048);
  biasq_k<<<dim3(2), tb, 0, stream>>>(psi_w, phi_b, biasq);
  pb_k<<<dim3(8), tb, 0, stream>>>(psi_b, wc0T, pb);

  // the whole 200-step recurrence in one persistent kernel
  loop_k<<<dim3(NBLK), tb, 0, stream>>>(
      h, Mt, whh0T, whh1T, wih1T, Bm, wyT, biasq, pb,
      b_ih0, b_hh0, b_ih1, b_hh1, y,
      s0, cs0, s1, cs1, g0part, g1part,
      partm, partl, partacc, cbuf, s_seq,
      bar, bcnt);

  // out = s_seq @ out_w.T + out_b   [12800, 1000]
  biggemm_k<<<dim3(100, 8), tb, 0, stream>>>(s_seq, out_wT, 1024, out_b, out, 1000, 1000);
}

// Round 8
// 51727.850 us; speedup vs baseline: 1.1377x; 1.1377x over previous
//
#include <hip/hip_runtime.h>
#include <math.h>

#define BB 64
#define RR 1024
#define TT 200
#define HH 512
#define VV 1000
#define GG 2048
#define NBLK 256
#define NTHR 256

typedef float vf4 __attribute__((ext_vector_type(4)));

__device__ __forceinline__ float sigmf(float x) { return 1.f / (1.f + __expf(-x)); }

// coherent scalar access (agent scope = MALL): for cross-block data inside a phase
__device__ __forceinline__ void cstore(float* p, float v) {
  __hip_atomic_store(p, v, __ATOMIC_RELAXED, __HIP_MEMORY_SCOPE_AGENT);
}
__device__ __forceinline__ float cload(const float* p) {
  return __hip_atomic_load(p, __ATOMIC_RELAXED, __HIP_MEMORY_SCOPE_AGENT);
}
__device__ __forceinline__ int armw(int* p, int v) {
  return __hip_atomic_fetch_add(p, v, __ATOMIC_RELAXED, __HIP_MEMORY_SCOPE_AGENT);
}

// ---------------- transpose: dst[n][m] = src[m*sstride + soff + n] ----------------
__global__ __launch_bounds__(256) void transpose_k(const float* __restrict__ src,
    float* __restrict__ dst, int Msrc, int Mdst, int N, int sstride, int soff) {
  __shared__ float tile[32][33];
  int mt = blockIdx.y * 32, ntb = blockIdx.x * 32;
  int tx = threadIdx.x & 31, ty = threadIdx.x >> 5;
  #pragma unroll
  for (int i = ty; i < 32; i += 8) {
    int m = mt + i, n = ntb + tx;
    tile[i][tx] = (m < Msrc && n < N) ? src[(size_t)m * sstride + soff + n] : 0.f;
  }
  __syncthreads();
  #pragma unroll
  for (int i = ty; i < 32; i += 8) {
    int n = ntb + i, m = mt + tx;
    if (n < N && m < Mdst) dst[(size_t)n * Mdst + m] = tile[tx][i];
  }
}

// ---------------- big GEMM: C[M][cld] = A[M][512] @ W[512][wld-slab] + bias ----------------
__global__ __launch_bounds__(256) void biggemm_k(const float* __restrict__ A,
    const float* __restrict__ W, int wld, const float* __restrict__ bias,
    float* __restrict__ C, int cld, int Nout) {
  int mt = blockIdx.x * 128, ntile = blockIdx.y * 128;
  __shared__ float As[16][132];
  __shared__ float Ws[16][132];
  int tid = threadIdx.x;
  int ty = tid >> 4, tx = tid & 15;
  float acc[8][8] = {};
  for (int k0 = 0; k0 < 512; k0 += 16) {
    {
      int row = tid >> 1, kc = (tid & 1) * 8;
      float4 a0 = *(const float4*)&A[(size_t)(mt + row) * 512 + k0 + kc];
      float4 a1 = *(const float4*)&A[(size_t)(mt + row) * 512 + k0 + kc + 4];
      As[kc + 0][row] = a0.x; As[kc + 1][row] = a0.y; As[kc + 2][row] = a0.z; As[kc + 3][row] = a0.w;
      As[kc + 4][row] = a1.x; As[kc + 5][row] = a1.y; As[kc + 6][row] = a1.z; As[kc + 7][row] = a1.w;
      int krow = tid >> 4, nc = (tid & 15) * 8;
      *(float4*)&Ws[krow][nc]     = *(const float4*)&W[(size_t)(k0 + krow) * wld + ntile + nc];
      *(float4*)&Ws[krow][nc + 4] = *(const float4*)&W[(size_t)(k0 + krow) * wld + ntile + nc + 4];
    }
    __syncthreads();
    #pragma unroll
    for (int kk = 0; kk < 16; kk++) {
      float4 a0 = *(float4*)&As[kk][ty * 8];
      float4 a1 = *(float4*)&As[kk][ty * 8 + 4];
      float4 w0 = *(float4*)&Ws[kk][tx * 8];
      float4 w1 = *(float4*)&Ws[kk][tx * 8 + 4];
      float av[8] = {a0.x, a0.y, a0.z, a0.w, a1.x, a1.y, a1.z, a1.w};
      float wv[8] = {w0.x, w0.y, w0.z, w0.w, w1.x, w1.y, w1.z, w1.w};
      #pragma unroll
      for (int i = 0; i < 8; i++)
        #pragma unroll
        for (int j = 0; j < 8; j++)
          acc[i][j] += av[i] * wv[j];
    }
    __syncthreads();
  }
  #pragma unroll
  for (int i = 0; i < 8; i++) {
    int m = mt + ty * 8 + i;
    #pragma unroll
    for (int j = 0; j < 8; j++) {
      int n = ntile + tx * 8 + j;
      if (n < Nout) C[(size_t)m * cld + n] = acc[i][j] + bias[n];
    }
  }
}

// ---------------- tiny setup kernels ----------------
__global__ __launch_bounds__(256) void biasq_k(const float* __restrict__ psi_w,
    const float* __restrict__ phi_b, float* __restrict__ biasq) {
  int i = blockIdx.x * 256 + threadIdx.x;
  float v = 0.f;
  for (int k = 0; k < 512; k++) v += psi_w[(size_t)k * 512 + i] * phi_b[k];
  biasq[i] = v;
}
__global__ __launch_bounds__(256) void pb_k(const float* __restrict__ psi_b,
    const float* __restrict__ wc0T, float* __restrict__ pb) {
  int n = blockIdx.x * 256 + threadIdx.x;
  float v = 0.f;
  for (int k = 0; k < 512; k++) v += psi_b[k] * wc0T[(size_t)k * 2048 + n];
  pb[n] = v;
}

// ================= persistent loop kernel =================
struct SmGemm { float Ask[64][68]; float Wsk[64][68]; };
struct SmAttn { float qs[HH]; float wacc[4][HH]; float wml[8]; int cflag; };

// hierarchical grid barrier: 16 groups x 16 blocks; RMW-poll; leader-only fences. (R5-proven)
__device__ __forceinline__ void gbar(int* bar, int k1) {
  __syncthreads();
  if (threadIdx.x == 0) {
    __threadfence();                                  // release
    int g = blockIdx.x >> 4;
    int old = armw(&bar[g * 32], 1);
    if ((old & 15) == 15) {
      int o2 = armw(&bar[512], 1);
      if ((o2 & 15) == 15)
        __hip_atomic_store(&bar[544], k1, __ATOMIC_RELAXED, __HIP_MEMORY_SCOPE_AGENT);
    }
    if ((blockIdx.x & 15) == 0) {
      while (armw(&bar[544], 0) < k1) __builtin_amdgcn_s_sleep(1);
      __hip_atomic_store(&bar[576 + g * 32], k1, __ATOMIC_RELAXED, __HIP_MEMORY_SCOPE_AGENT);
    } else {
      while (armw(&bar[576 + g * 32], 0) < k1) __builtin_amdgcn_s_sleep(1);
    }
    __threadfence();                                  // acquire
  }
  __syncthreads();
}

// 64x64 output tile, K=128 starting at k0. A rows stride 512. (R5-proven)
__device__ __forceinline__ void sgemm_tile(const float* A, const float* W, int wld, int k0,
                                           float* Cout, int N, int nt, SmGemm* sm) {
  int tid = threadIdx.x;
  int b0 = (tid >> 4) * 4, n0 = (tid & 15) * 4;
  float acc[4][4] = {};
  for (int kb = 0; kb < 128; kb += 64) {
    {
      int brow = tid & 63;
      int kcb = (tid >> 6) * 16;
      const float* ap = A + (size_t)brow * 512 + k0 + kb + kcb;
      #pragma unroll
      for (int j = 0; j < 4; j++) {
        float4 a4 = *(const float4*)(ap + j * 4);
        sm->Ask[kcb + j * 4 + 0][brow] = a4.x;
        sm->Ask[kcb + j * 4 + 1][brow] = a4.y;
        sm->Ask[kcb + j * 4 + 2][brow] = a4.z;
        sm->Ask[kcb + j * 4 + 3][brow] = a4.w;
      }
      int nc = (tid & 15) * 4;
      #pragma unroll
      for (int j = 0; j < 4; j++) {
        int krow = (tid >> 4) + j * 16;
        *(float4*)&sm->Wsk[krow][nc] =
            *(const float4*)&W[(size_t)(k0 + kb + krow) * wld + nt * 64 + nc];
      }
    }
    __syncthreads();
    #pragma unroll
    for (int kk = 0; kk < 64; kk++) {
      float4 a = *(float4*)&sm->Ask[kk][b0];
      float4 w = *(float4*)&sm->Wsk[kk][n0];
      acc[0][0] += a.x * w.x; acc[0][1] += a.x * w.y; acc[0][2] += a.x * w.z; acc[0][3] += a.x * w.w;
      acc[1][0] += a.y * w.x; acc[1][1] += a.y * w.y; acc[1][2] += a.y * w.z; acc[1][3] += a.y * w.w;
      acc[2][0] += a.z * w.x; acc[2][1] += a.z * w.y; acc[2][2] += a.z * w.z; acc[2][3] += a.z * w.w;
      acc[3][0] += a.w * w.x; acc[3][1] += a.w * w.y; acc[3][2] += a.w * w.z; acc[3][3] += a.w * w.w;
    }
    __syncthreads();
  }
  float* C2 = Cout + (size_t)nt * 64;
  #pragma unroll
  for (int i = 0; i < 4; i++) {
    float4 v = make_float4(acc[i][0], acc[i][1], acc[i][2], acc[i][3]);
    *(float4*)&C2[(size_t)(b0 + i) * N + n0] = v;
  }
}

// attention with inline q: tile = b*4+ch, chunk = 256 rows, wave = 64 rows.
// batch-4 online softmax: 4 independent shfl chains, one rescale per 4 rows.
__device__ __forceinline__ void attn_tile(int tile, int t, const float* h,
    const float* s1, const float* Mt, const float* biasq,
    float* partm, float* partl, float* partacc, float* cbuf,
    int* bcnt, SmAttn* sm) {
  int tid = threadIdx.x;
  int b = tile >> 2, ch = tile & 3;
  // stage s1 row, then q = biasq + s1row @ Mt  (each thread: outputs d=tid, d=tid+256)
  for (int d = tid; d < HH; d += NTHR) sm->wacc[0][d] = s1[(size_t)b * HH + d];
  __syncthreads();
  {
    float a0 = biasq[tid], a1 = biasq[tid + 256];
    #pragma unroll 8
    for (int k = 0; k < 512; k++) {
      float sv = sm->wacc[0][k];
      a0 += sv * Mt[(size_t)k * 512 + tid];
      a1 += sv * Mt[(size_t)k * 512 + tid + 256];
    }
    sm->qs[tid] = a0; sm->qs[tid + 256] = a1;
  }
  __syncthreads();
  int wave = tid >> 6, lane = tid & 63;
  float qreg[8];
  {
    const float* qp = sm->qs + lane * 8;
    #pragma unroll
    for (int j = 0; j < 8; j++) qreg[j] = qp[j];
  }
  float m = -INFINITY, l = 0.f;
  float acc[8] = {};
  const float* hbase = h + ((size_t)b * RR + ch * 256 + wave * 64) * HH + lane * 8;
  vf4 c[4][2], n[4][2];
  #pragma unroll
  for (int k = 0; k < 4; k++) {
    c[k][0] = *(const vf4*)(hbase + (size_t)k * HH);
    c[k][1] = *(const vf4*)(hbase + (size_t)k * HH + 4);
  }
  for (int bt = 0; bt < 16; bt++) {
    if (bt < 15) {
      #pragma unroll
      for (int k = 0; k < 4; k++) {
        n[k][0] = *(const vf4*)(hbase + (size_t)(bt * 4 + 4 + k) * HH);
        n[k][1] = *(const vf4*)(hbase + (size_t)(bt * 4 + 4 + k) * HH + 4);
      }
    }
    float p[4];
    #pragma unroll
    for (int k = 0; k < 4; k++) {
      vf4 u = c[k][0], v = c[k][1];
      p[k] = qreg[0] * u.x + qreg[1] * u.y + qreg[2] * u.z + qreg[3] * u.w
           + qreg[4] * v.x + qreg[5] * v.y + qreg[6] * v.z + qreg[7] * v.w;
    }
    #pragma unroll
    for (int off = 32; off > 0; off >>= 1) {
      #pragma unroll
      for (int k = 0; k < 4; k++) p[k] += __shfl_xor(p[k], off, 64);
    }
    float bm = fmaxf(fmaxf(p[0], p[1]), fmaxf(p[2], p[3]));
    float mn = fmaxf(m, bm);
    float scl = __expf(m - mn);
    float w0 = __expf(p[0] - mn), w1 = __expf(p[1] - mn);
    float w2 = __expf(p[2] - mn), w3 = __expf(p[3] - mn);
    l = l * scl + w0 + w1 + w2 + w3;
    #pragma unroll
    for (int j = 0; j < 4; j++) {
      acc[j]     = acc[j]     * scl + w0 * c[0][0][j] + w1 * c[1][0][j] + w2 * c[2][0][j] + w3 * c[3][0][j];
      acc[j + 4] = acc[j + 4] * scl + w0 * c[0][1][j] + w1 * c[1][1][j] + w2 * c[2][1][j] + w3 * c[3][1][j];
    }
    m = mn;
    #pragma unroll
    for (int k = 0; k < 4; k++) { c[k][0] = n[k][0]; c[k][1] = n[k][1]; }
  }
  #pragma unroll
  for (int j = 0; j < 8; j++) sm->wacc[wave][lane * 8 + j] = acc[j];
  if (lane == 0) { sm->wml[wave] = m; sm->wml[4 + wave] = l; }
  __syncthreads();
  float M = fmaxf(fmaxf(sm->wml[0], sm->wml[1]), fmaxf(sm->wml[2], sm->wml[3]));
  float e0 = __expf(sm->wml[0] - M), e1 = __expf(sm->wml[1] - M);
  float e2 = __expf(sm->wml[2] - M), e3 = __expf(sm->wml[3] - M);
  if (tid == 0) {
    cstore(&partm[b * 4 + ch], M);
    cstore(&partl[b * 4 + ch], sm->wml[4] * e0 + sm->wml[5] * e1 + sm->wml[6] * e2 + sm->wml[7] * e3);
  }
  for (int d = tid; d < HH; d += NTHR)
    cstore(&partacc[((size_t)b * 4 + ch) * HH + d],
           sm->wacc[0][d] * e0 + sm->wacc[1][d] * e1 + sm->wacc[2][d] * e2 + sm->wacc[3][d] * e3);
  // gating: 4th finisher for batch b combines (order-independent math)
  __syncthreads();                       // drains all waves' stores (vmcnt)
  if (tid == 0) sm->cflag = armw(&bcnt[b], 1);
  __syncthreads();
  if (sm->cflag == 4 * t + 3) {
    float Mx = -INFINITY;
    #pragma unroll
    for (int p = 0; p < 4; p++) Mx = fmaxf(Mx, cload(&partm[b * 4 + p]));
    float sc2[4]; float L = 0.f;
    #pragma unroll
    for (int p = 0; p < 4; p++) {
      sc2[p] = __expf(cload(&partm[b * 4 + p]) - Mx);
      L += sc2[p] * cload(&partl[b * 4 + p]);
    }
    float inv = 1.f / L;
    for (int d = tid; d < HH; d += NTHR) {
      float v = 0.f;
      #pragma unroll
      for (int p = 0; p < 4; p++) v += sc2[p] * cload(&partacc[((size_t)b * 4 + p) * HH + d]);
      cbuf[b * HH + d] = v * inv;        // normal store; consumed after fenced barrier
    }
  }
}

__global__ __launch_bounds__(NTHR) void loop_k(
    const float* h, const float* Mt, const float* whh0T, const float* whh1T,
    const float* wih1T, const float* Bm, const float* wyT,
    const float* biasq, const float* pb,
    const float* b_ih0, const float* b_hh0,
    const float* b_ih1, const float* b_hh1, const int* y,
    float* s0, float* cs0, float* s1, float* cs1,
    float* g0part, float* g1part,
    float* partm, float* partl, float* partacc, float* cbuf, float* s_seq,
    int* bar, int* bcnt) {
  __shared__ __align__(16) char smraw[sizeof(SmGemm)];
  SmGemm* smg = (SmGemm*)smraw;
  SmAttn* sma = (SmAttn*)smraw;
  int bid = blockIdx.x, tid = threadIdx.x;
  int bk = 0;
  for (int t = 0; t < TT; t++) {
    // Phase A: attn (inline q, gated combine) + g0h (s0@whh0, tiles 0-127) + g1h (s1@whh1, 128-255)
    attn_tile(bid, t, h, s1, Mt, biasq, partm, partl, partacc, cbuf, bcnt, sma);
    __syncthreads();                     // LDS handoff: SmAttn -> SmGemm (cflag overlap)
    {
      int nt = bid & 31, kc = (bid >> 5) & 3;
      if (bid < 128)
        sgemm_tile(s0, whh0T, GG, kc * 128, g0part + (size_t)(4 + kc) * BB * GG, GG, nt, smg);
      else
        sgemm_tile(s1, whh1T, GG, kc * 128, g1part + (size_t)(4 + kc) * BB * GG, GG, nt, smg);
    }
    gbar(bar, ++bk);
    // Phase B: capp @ Bm -> g0part slabs 0-3
    if (bid < 128) {
      int nt = bid & 31, kc = bid >> 5;
      sgemm_tile(cbuf, Bm, GG, kc * 128, g0part + (size_t)kc * BB * GG, GG, nt, smg);
    }
    gbar(bar, ++bk);
    // Phase C: act0 -> s0, cs0
    {
      int idx = bid * NTHR + tid;
      if (idx < BB * HH) {
        int b = idx >> 9, jj = idx & 511;
        int yv = y[b * TT + t];
        float g[4];
        #pragma unroll
        for (int gi = 0; gi < 4; gi++) {
          int j = gi * 512 + jj;
          float v = b_ih0[j] + b_hh0[j] + pb[j] + wyT[(size_t)yv * GG + j];
          #pragma unroll
          for (int p = 0; p < 8; p++) v += g0part[((size_t)p * BB + b) * GG + j];
          g[gi] = v;
        }
        float cn = sigmf(g[1]) * cs0[idx] + sigmf(g[0]) * tanhf(g[2]);
        cs0[idx] = cn;
        s0[idx] = sigmf(g[3]) * tanhf(cn);
      }
    }
    gbar(bar, ++bk);
    // Phase D: s0 @ wih1 -> g1part slabs 0-3
    if (bid < 128) {
      int nt = bid & 31, kc = bid >> 5;
      sgemm_tile(s0, wih1T, GG, kc * 128, g1part + (size_t)kc * BB * GG, GG, nt, smg);
    }
    gbar(bar, ++bk);
    // Phase E: act1 -> s1, cs1, s_seq (NT store: keep h L3-resident)
    {
      int idx = bid * NTHR + tid;
      if (idx < BB * HH) {
        int b = idx >> 9, jj = idx & 511;
        float g[4];
        #pragma unroll
        for (int gi = 0; gi < 4; gi++) {
          int j = gi * 512 + jj;
          float v = b_ih1[j] + b_hh1[j];
          #pragma unroll
          for (int p = 0; p < 8; p++) v += g1part[((size_t)p * BB + b) * GG + j];
          g[gi] = v;
        }
        float cn = sigmf(g[1]) * cs1[idx] + sigmf(g[0]) * tanhf(g[2]);
        cs1[idx] = cn;
        float hv = sigmf(g[3]) * tanhf(cn);
        s1[idx] = hv;
        __builtin_nontemporal_store(hv, &s_seq[((size_t)b * TT + t) * HH + jj]);
      }
    }
    gbar(bar, ++bk);
  }
}

extern "C" void kernel_launch(void* const* d_in, const int* in_sizes, int n_in,
                              void* d_out, int out_size, void* d_ws, size_t ws_size,
                              hipStream_t stream) {
  (void)in_sizes; (void)n_in; (void)out_size; (void)ws_size;
  const float* h     = (const float*)d_in[0];
  const int*   y     = (const int*)d_in[1];
  const float* phi_w = (const float*)d_in[2];
  const float* phi_b = (const float*)d_in[3];
  const float* psi_w = (const float*)d_in[4];
  const float* psi_b = (const float*)d_in[5];
  const float* w_ih0 = (const float*)d_in[6];
  const float* w_hh0 = (const float*)d_in[7];
  const float* b_ih0 = (const float*)d_in[8];
  const float* b_hh0 = (const float*)d_in[9];
  const float* w_ih1 = (const float*)d_in[10];
  const float* w_hh1 = (const float*)d_in[11];
  const float* b_ih1 = (const float*)d_in[12];
  const float* b_hh1 = (const float*)d_in[13];
  const float* out_w = (const float*)d_in[14];
  const float* out_b = (const float*)d_in[15];
  float* out = (float*)d_out;

  float* ws = (float*)d_ws;
  size_t off = 0;
  auto alloc = [&](size_t n) { size_t o = off; off += (n + 63) & ~(size_t)63; return o; };
  float* barf   = ws + alloc(1216);                   // bar ints [0..1151] | bcnt [1152..1215]
  float* st     = ws + alloc(4 * BB * HH);
  float* psi_wT = ws + alloc(HH * HH);
  float* phi_wT = ws + alloc(HH * HH);
  float* Mt     = ws + alloc(HH * HH);
  float* wc0T   = ws + alloc(HH * GG);
  float* Bm     = ws + alloc(HH * GG);
  float* whh0T  = ws + alloc(HH * GG);
  float* wih1T  = ws + alloc(HH * GG);
  float* whh1T  = ws + alloc(HH * GG);
  float* wyT    = ws + alloc((size_t)VV * GG);
  float* out_wT = ws + alloc((size_t)HH * 1024);
  float* biasq  = ws + alloc(HH);
  float* pb     = ws + alloc(GG);
  float* zeros  = ws + alloc(GG);
  float* s0 = st, *cs0 = st + BB * HH, *s1 = st + 2 * BB * HH, *cs1 = st + 3 * BB * HH;
  float* cbuf   = ws + alloc(BB * HH);
  float* g0part = ws + alloc((size_t)8 * BB * GG);
  float* g1part = ws + alloc((size_t)8 * BB * GG);
  float* partm  = ws + alloc(BB * 4);
  float* partl  = ws + alloc(BB * 4);
  float* partacc= ws + alloc((size_t)BB * 4 * HH);
  float* s_seq  = ws + alloc((size_t)BB * TT * HH);

  int* bar  = (int*)barf;
  int* bcnt = (int*)barf + 1152;

  hipMemsetAsync(barf, 0, (1216 + (size_t)4 * BB * HH) * sizeof(float), stream);
  hipMemsetAsync(zeros, 0, GG * sizeof(float), stream);

  dim3 tb(256);
  transpose_k<<<dim3(16, 16), tb, 0, stream>>>(psi_w, psi_wT, 512, 512, 512, 512, 0);
  transpose_k<<<dim3(16, 16), tb, 0, stream>>>(phi_w, phi_wT, 512, 512, 512, 512, 0);
  transpose_k<<<dim3(16, 64), tb, 0, stream>>>(w_ih0, wc0T, 2048, 2048, 512, 1512, 1000);
  transpose_k<<<dim3(16, 64), tb, 0, stream>>>(w_hh0, whh0T, 2048, 2048, 512, 512, 0);
  transpose_k<<<dim3(16, 64), tb, 0, stream>>>(w_ih1, wih1T, 2048, 2048, 512, 512, 0);
  transpose_k<<<dim3(16, 64), tb, 0, stream>>>(w_hh1, whh1T, 2048, 2048, 512, 512, 0);
  transpose_k<<<dim3(32, 64), tb, 0, stream>>>(w_ih0, wyT, 2048, 2048, 1000, 1512, 0);
  transpose_k<<<dim3(16, 32), tb, 0, stream>>>(out_w, out_wT, 1000, 1024, 512, 512, 0);

  // Mt = phi_w^T @ psi_w ; Bm = psi_wT @ wc0T ; bias folds
  biggemm_k<<<dim3(4, 4), tb, 0, stream>>>(phi_wT, psi_w, 512, zeros, Mt, 512, 512);
  biggemm_k<<<dim3(4, 16), tb, 0, stream>>>(psi_wT, wc0T, 2048, zeros, Bm, 2048, 2048);
  biasq_k<<<dim3(2), tb, 0, stream>>>(psi_w, phi_b, biasq);
  pb_k<<<dim3(8), tb, 0, stream>>>(psi_b, wc0T, pb);

  // the whole 200-step recurrence in one persistent kernel
  loop_k<<<dim3(NBLK), tb, 0, stream>>>(
      h, Mt, whh0T, whh1T, wih1T, Bm, wyT, biasq, pb,
      b_ih0, b_hh0, b_ih1, b_hh1, y,
      s0, cs0, s1, cs1, g0part, g1part,
      partm, partl, partacc, cbuf, s_seq,
      bar, bcnt);

  // out = s_seq @ out_w.T + out_b   [12800, 1000]
  biggemm_k<<<dim3(100, 8), tb, 0, stream>>>(s_seq, out_wT, 1024, out_b, out, 1000, 1000);
}

// Round 11
// 16731.026 us; speedup vs baseline: 3.5175x; 3.0917x over previous
//
#include <hip/hip_runtime.h>
#include <math.h>

#define BB 64
#define RR 1024
#define TT 200
#define HH 512
#define VV 1000
#define GG 2048

typedef float vf4 __attribute__((ext_vector_type(4)));

__device__ __forceinline__ float sigmf(float x) { return 1.f / (1.f + __expf(-x)); }

// coherent scalar access (agent scope): cross-block data within one kernel (R5-proven)
__device__ __forceinline__ void cstore(float* p, float v) {
  __hip_atomic_store(p, v, __ATOMIC_RELAXED, __HIP_MEMORY_SCOPE_AGENT);
}
__device__ __forceinline__ float cload(const float* p) {
  return __hip_atomic_load(p, __ATOMIC_RELAXED, __HIP_MEMORY_SCOPE_AGENT);
}
__device__ __forceinline__ int armw(int* p, int v) {
  return __hip_atomic_fetch_add(p, v, __ATOMIC_RELAXED, __HIP_MEMORY_SCOPE_AGENT);
}

// ---------------- transpose: dst[n][m] = src[m*sstride + soff + n] ----------------
__global__ __launch_bounds__(256) void transpose_k(const float* __restrict__ src,
    float* __restrict__ dst, int Msrc, int Mdst, int N, int sstride, int soff) {
  __shared__ float tile[32][33];
  int mt = blockIdx.y * 32, ntb = blockIdx.x * 32;
  int tx = threadIdx.x & 31, ty = threadIdx.x >> 5;
  #pragma unroll
  for (int i = ty; i < 32; i += 8) {
    int m = mt + i, n = ntb + tx;
    tile[i][tx] = (m < Msrc && n < N) ? src[(size_t)m * sstride + soff + n] : 0.f;
  }
  __syncthreads();
  #pragma unroll
  for (int i = ty; i < 32; i += 8) {
    int n = ntb + i, m = mt + tx;
    if (n < N && m < Mdst) dst[(size_t)n * Mdst + m] = tile[tx][i];
  }
}

// ---------------- big GEMM: C[M][cld] = A[M][512] @ W[512][wld-slab] + bias ----------------
__global__ __launch_bounds__(256) void biggemm_k(const float* __restrict__ A,
    const float* __restrict__ W, int wld, const float* __restrict__ bias,
    float* __restrict__ C, int cld, int Nout) {
  int mt = blockIdx.x * 128, ntile = blockIdx.y * 128;
  __shared__ float As[16][132];
  __shared__ float Ws[16][132];
  int tid = threadIdx.x;
  int ty = tid >> 4, tx = tid & 15;
  float acc[8][8] = {};
  for (int k0 = 0; k0 < 512; k0 += 16) {
    {
      int row = tid >> 1, kc = (tid & 1) * 8;
      float4 a0 = *(const float4*)&A[(size_t)(mt + row) * 512 + k0 + kc];
      float4 a1 = *(const float4*)&A[(size_t)(mt + row) * 512 + k0 + kc + 4];
      As[kc + 0][row] = a0.x; As[kc + 1][row] = a0.y; As[kc + 2][row] = a0.z; As[kc + 3][row] = a0.w;
      As[kc + 4][row] = a1.x; As[kc + 5][row] = a1.y; As[kc + 6][row] = a1.z; As[kc + 7][row] = a1.w;
      int krow = tid >> 4, nc = (tid & 15) * 8;
      *(float4*)&Ws[krow][nc]     = *(const float4*)&W[(size_t)(k0 + krow) * wld + ntile + nc];
      *(float4*)&Ws[krow][nc + 4] = *(const float4*)&W[(size_t)(k0 + krow) * wld + ntile + nc + 4];
    }
    __syncthreads();
    #pragma unroll
    for (int kk = 0; kk < 16; kk++) {
      float4 a0 = *(float4*)&As[kk][ty * 8];
      float4 a1 = *(float4*)&As[kk][ty * 8 + 4];
      float4 w0 = *(float4*)&Ws[kk][tx * 8];
      float4 w1 = *(float4*)&Ws[kk][tx * 8 + 4];
      float av[8] = {a0.x, a0.y, a0.z, a0.w, a1.x, a1.y, a1.z, a1.w};
      float wv[8] = {w0.x, w0.y, w0.z, w0.w, w1.x, w1.y, w1.z, w1.w};
      #pragma unroll
      for (int i = 0; i < 8; i++)
        #pragma unroll
        for (int j = 0; j < 8; j++)
          acc[i][j] += av[i] * wv[j];
    }
    __syncthreads();
  }
  #pragma unroll
  for (int i = 0; i < 8; i++) {
    int m = mt + ty * 8 + i;
    #pragma unroll
    for (int j = 0; j < 8; j++) {
      int n = ntile + tx * 8 + j;
      if (n < Nout) C[(size_t)m * cld + n] = acc[i][j] + bias[n];
    }
  }
}

// ---------------- tiny setup kernels ----------------
__global__ __launch_bounds__(256) void biasq_k(const float* __restrict__ psi_w,
    const float* __restrict__ phi_b, float* __restrict__ biasq) {
  int i = blockIdx.x * 256 + threadIdx.x;
  float v = 0.f;
  for (int k = 0; k < 512; k++) v += psi_w[(size_t)k * 512 + i] * phi_b[k];
  biasq[i] = v;
}
__global__ __launch_bounds__(256) void pb_k(const float* __restrict__ psi_b,
    const float* __restrict__ wc0T, float* __restrict__ pb) {
  int n = blockIdx.x * 256 + threadIdx.x;
  float v = 0.f;
  for (int k = 0; k < 512; k++) v += psi_b[k] * wc0T[(size_t)k * 2048 + n];
  pb[n] = v;
}

// ---------------- shared 64x64 K=128 GEMM tile (R5-proven) ----------------
struct SmGemm { float Ask[64][68]; float Wsk[64][68]; };
struct SmAttn { float qs[HH]; float wacc[4][HH]; float wml[8]; };

__device__ __forceinline__ void sgemm_tile(const float* A, const float* W, int wld, int k0,
                                           float* Cout, int N, int nt, SmGemm* sm) {
  int tid = threadIdx.x;
  int b0 = (tid >> 4) * 4, n0 = (tid & 15) * 4;
  float acc[4][4] = {};
  for (int kb = 0; kb < 128; kb += 64) {
    {
      int brow = tid & 63;
      int kcb = (tid >> 6) * 16;
      const float* ap = A + (size_t)brow * 512 + k0 + kb + kcb;
      #pragma unroll
      for (int j = 0; j < 4; j++) {
        float4 a4 = *(const float4*)(ap + j * 4);
        sm->Ask[kcb + j * 4 + 0][brow] = a4.x;
        sm->Ask[kcb + j * 4 + 1][brow] = a4.y;
        sm->Ask[kcb + j * 4 + 2][brow] = a4.z;
        sm->Ask[kcb + j * 4 + 3][brow] = a4.w;
      }
      int nc = (tid & 15) * 4;
      #pragma unroll
      for (int j = 0; j < 4; j++) {
        int krow = (tid >> 4) + j * 16;
        *(float4*)&sm->Wsk[krow][nc] =
            *(const float4*)&W[(size_t)(k0 + kb + krow) * wld + nt * 64 + nc];
      }
    }
    __syncthreads();
    #pragma unroll
    for (int kk = 0; kk < 64; kk++) {
      float4 a = *(float4*)&sm->Ask[kk][b0];
      float4 w = *(float4*)&sm->Wsk[kk][n0];
      acc[0][0] += a.x * w.x; acc[0][1] += a.x * w.y; acc[0][2] += a.x * w.z; acc[0][3] += a.x * w.w;
      acc[1][0] += a.y * w.x; acc[1][1] += a.y * w.y; acc[1][2] += a.y * w.z; acc[1][3] += a.y * w.w;
      acc[2][0] += a.z * w.x; acc[2][1] += a.z * w.y; acc[2][2] += a.z * w.z; acc[2][3] += a.z * w.w;
      acc[3][0] += a.w * w.x; acc[3][1] += a.w * w.y; acc[3][2] += a.w * w.z; acc[3][3] += a.w * w.w;
    }
    __syncthreads();
  }
  float* C2 = Cout + (size_t)nt * 64;
  #pragma unroll
  for (int i = 0; i < 4; i++) {
    float4 v = make_float4(acc[i][0], acc[i][1], acc[i][2], acc[i][3]);
    *(float4*)&C2[(size_t)(b0 + i) * N + n0] = v;
  }
}

// ================= K1: attn (inline q, gated combine) + hidden-state GEMMs =================
// blocks 0..511: attn, b=bid>>3, ch=bid&7 (128 rows each, 32/wave, batch-4 softmax)
// blocks 512..639: s0@whh0 -> g0part slabs 4..7 ; 640..767: s1@whh1 -> g1part slabs 4..7
__global__ __launch_bounds__(256) void step1_k(
    const float* __restrict__ h, const float* __restrict__ Mt,
    const float* __restrict__ biasq,
    const float* __restrict__ whh0T, const float* __restrict__ whh1T,
    const float* s0, const float* s1,
    float* g0part, float* g1part,
    float* partm, float* partl, float* partacc, float* cbuf,
    int* bcnt, int t) {
  __shared__ __align__(16) char smraw[sizeof(SmGemm)];
  int bid = blockIdx.x, tid = threadIdx.x;
  if (bid >= 512) {
    SmGemm* smg = (SmGemm*)smraw;
    int idx = bid - 512;
    int nt = idx & 31, kc = (idx >> 5) & 3;
    if (idx < 128)
      sgemm_tile(s0, whh0T, GG, kc * 128, g0part + (size_t)(4 + kc) * BB * GG, GG, nt, smg);
    else
      sgemm_tile(s1, whh1T, GG, kc * 128, g1part + (size_t)(4 + kc) * BB * GG, GG, nt, smg);
    return;
  }
  SmAttn* sm = (SmAttn*)smraw;
  int b = bid >> 3, ch = bid & 7;
  // inline q = biasq + s1[b] @ Mt
  for (int d = tid; d < HH; d += 256) sm->wacc[0][d] = s1[(size_t)b * HH + d];
  __syncthreads();
  {
    float a0 = biasq[tid], a1 = biasq[tid + 256];
    #pragma unroll 8
    for (int k = 0; k < 512; k++) {
      float sv = sm->wacc[0][k];
      a0 += sv * Mt[(size_t)k * 512 + tid];
      a1 += sv * Mt[(size_t)k * 512 + tid + 256];
    }
    sm->qs[tid] = a0; sm->qs[tid + 256] = a1;
  }
  __syncthreads();
  int wave = tid >> 6, lane = tid & 63;
  float qreg[8];
  {
    const float* qp = sm->qs + lane * 8;
    #pragma unroll
    for (int j = 0; j < 8; j++) qreg[j] = qp[j];
  }
  float m = -INFINITY, l = 0.f;
  float acc[8] = {};
  const float* hbase = h + ((size_t)b * RR + ch * 128 + wave * 32) * HH + lane * 8;
  vf4 c[4][2], n[4][2];
  #pragma unroll
  for (int k = 0; k < 4; k++) {
    c[k][0] = *(const vf4*)(hbase + (size_t)k * HH);
    c[k][1] = *(const vf4*)(hbase + (size_t)k * HH + 4);
  }
  for (int bt = 0; bt < 8; bt++) {
    if (bt < 7) {
      #pragma unroll
      for (int k = 0; k < 4; k++) {
        n[k][0] = *(const vf4*)(hbase + (size_t)(bt * 4 + 4 + k) * HH);
        n[k][1] = *(const vf4*)(hbase + (size_t)(bt * 4 + 4 + k) * HH + 4);
      }
    }
    float p[4];
    #pragma unroll
    for (int k = 0; k < 4; k++) {
      vf4 u = c[k][0], v = c[k][1];
      p[k] = qreg[0] * u.x + qreg[1] * u.y + qreg[2] * u.z + qreg[3] * u.w
           + qreg[4] * v.x + qreg[5] * v.y + qreg[6] * v.z + qreg[7] * v.w;
    }
    #pragma unroll
    for (int off = 32; off > 0; off >>= 1) {
      #pragma unroll
      for (int k = 0; k < 4; k++) p[k] += __shfl_xor(p[k], off, 64);
    }
    float bm = fmaxf(fmaxf(p[0], p[1]), fmaxf(p[2], p[3]));
    float mn = fmaxf(m, bm);
    float scl = __expf(m - mn);
    float w0 = __expf(p[0] - mn), w1 = __expf(p[1] - mn);
    float w2 = __expf(p[2] - mn), w3 = __expf(p[3] - mn);
    l = l * scl + w0 + w1 + w2 + w3;
    #pragma unroll
    for (int j = 0; j < 4; j++) {
      acc[j]     = acc[j]     * scl + w0 * c[0][0][j] + w1 * c[1][0][j] + w2 * c[2][0][j] + w3 * c[3][0][j];
      acc[j + 4] = acc[j + 4] * scl + w0 * c[0][1][j] + w1 * c[1][1][j] + w2 * c[2][1][j] + w3 * c[3][1][j];
    }
    m = mn;
    #pragma unroll
    for (int k = 0; k < 4; k++) { c[k][0] = n[k][0]; c[k][1] = n[k][1]; }
  }
  #pragma unroll
  for (int j = 0; j < 8; j++) sm->wacc[wave][lane * 8 + j] = acc[j];
  if (lane == 0) { sm->wml[wave] = m; sm->wml[4 + wave] = l; }
  __syncthreads();
  float M = fmaxf(fmaxf(sm->wml[0], sm->wml[1]), fmaxf(sm->wml[2], sm->wml[3]));
  float e0 = __expf(sm->wml[0] - M), e1 = __expf(sm->wml[1] - M);
  float e2 = __expf(sm->wml[2] - M), e3 = __expf(sm->wml[3] - M);
  if (tid == 0) {
    cstore(&partm[b * 8 + ch], M);
    cstore(&partl[b * 8 + ch], sm->wml[4] * e0 + sm->wml[5] * e1 + sm->wml[6] * e2 + sm->wml[7] * e3);
  }
  for (int d = tid; d < HH; d += 256)
    cstore(&partacc[((size_t)b * 8 + ch) * HH + d],
           sm->wacc[0][d] * e0 + sm->wacc[1][d] * e1 + sm->wacc[2][d] * e2 + sm->wacc[3][d] * e3);
  __syncthreads();                       // all waves' partial stores issued
  __shared__ int cflag;
  if (tid == 0) { __threadfence(); cflag = armw(&bcnt[b], 1); }
  __syncthreads();
  if (cflag == 8 * t + 7) {              // 8th finisher for b combines (order-independent)
    float Mx = -INFINITY;
    #pragma unroll
    for (int p = 0; p < 8; p++) Mx = fmaxf(Mx, cload(&partm[b * 8 + p]));
    float sc2[8]; float L = 0.f;
    #pragma unroll
    for (int p = 0; p < 8; p++) {
      sc2[p] = __expf(cload(&partm[b * 8 + p]) - Mx);
      L += sc2[p] * cload(&partl[b * 8 + p]);
    }
    float inv = 1.f / L;
    for (int d = tid; d < HH; d += 256) {
      float v = 0.f;
      #pragma unroll
      for (int p = 0; p < 8; p++) v += sc2[p] * cload(&partacc[((size_t)b * 8 + p) * HH + d]);
      cbuf[b * HH + d] = v * inv;        // consumed next kernel
    }
  }
}

// ================= K2 / K4: single 64x64-tile GEMM kernels =================
__global__ __launch_bounds__(256) void gemmB_k(const float* __restrict__ cbuf,
    const float* __restrict__ Bm, float* g0part) {
  __shared__ __align__(16) SmGemm smg;
  int nt = blockIdx.x & 31, kc = blockIdx.x >> 5;
  sgemm_tile(cbuf, Bm, GG, kc * 128, g0part + (size_t)kc * BB * GG, GG, nt, &smg);
}
__global__ __launch_bounds__(256) void gemmI_k(const float* __restrict__ s0,
    const float* __restrict__ wih1T, float* g1part) {
  __shared__ __align__(16) SmGemm smg;
  int nt = blockIdx.x & 31, kc = blockIdx.x >> 5;
  sgemm_tile(s0, wih1T, GG, kc * 128, g1part + (size_t)kc * BB * GG, GG, nt, &smg);
}

// ================= K3: act0 ; K5: act1 =================
__global__ __launch_bounds__(256) void act0_k(const float* __restrict__ gpart,
    const float* __restrict__ b_ih, const float* __restrict__ b_hh,
    const float* __restrict__ pb, const float* __restrict__ wyT,
    const int* __restrict__ y, int t,
    float* __restrict__ s0, float* __restrict__ cs0) {
  int idx = blockIdx.x * 256 + threadIdx.x;
  int b = idx >> 9, jj = idx & 511;
  int yv = y[b * TT + t];
  float g[4];
  #pragma unroll
  for (int gi = 0; gi < 4; gi++) {
    int j = gi * 512 + jj;
    float v = b_ih[j] + b_hh[j] + pb[j] + wyT[(size_t)yv * GG + j];
    #pragma unroll
    for (int p = 0; p < 8; p++) v += gpart[((size_t)p * BB + b) * GG + j];
    g[gi] = v;
  }
  float cn = sigmf(g[1]) * cs0[idx] + sigmf(g[0]) * tanhf(g[2]);
  cs0[idx] = cn;
  s0[idx] = sigmf(g[3]) * tanhf(cn);
}

__global__ __launch_bounds__(256) void act1_k(const float* __restrict__ gpart,
    const float* __restrict__ b_ih, const float* __restrict__ b_hh,
    int t, float* __restrict__ s1, float* __restrict__ cs1, float* __restrict__ s_seq) {
  int idx = blockIdx.x * 256 + threadIdx.x;
  int b = idx >> 9, jj = idx & 511;
  float g[4];
  #pragma unroll
  for (int gi = 0; gi < 4; gi++) {
    int j = gi * 512 + jj;
    float v = b_ih[j] + b_hh[j];
    #pragma unroll
    for (int p = 0; p < 8; p++) v += gpart[((size_t)p * BB + b) * GG + j];
    g[gi] = v;
  }
  float cn = sigmf(g[1]) * cs1[idx] + sigmf(g[0]) * tanhf(g[2]);
  cs1[idx] = cn;
  float hv = sigmf(g[3]) * tanhf(cn);
  s1[idx] = hv;
  __builtin_nontemporal_store(hv, &s_seq[((size_t)b * TT + t) * HH + jj]);
}

extern "C" void kernel_launch(void* const* d_in, const int* in_sizes, int n_in,
                              void* d_out, int out_size, void* d_ws, size_t ws_size,
                              hipStream_t stream) {
  (void)in_sizes; (void)n_in; (void)out_size; (void)ws_size;
  const float* h     = (const float*)d_in[0];
  const int*   y     = (const int*)d_in[1];
  const float* phi_w = (const float*)d_in[2];
  const float* phi_b = (const float*)d_in[3];
  const float* psi_w = (const float*)d_in[4];
  const float* psi_b = (const float*)d_in[5];
  const float* w_ih0 = (const float*)d_in[6];
  const float* w_hh0 = (const float*)d_in[7];
  const float* b_ih0 = (const float*)d_in[8];
  const float* b_hh0 = (const float*)d_in[9];
  const float* w_ih1 = (const float*)d_in[10];
  const float* w_hh1 = (const float*)d_in[11];
  const float* b_ih1 = (const float*)d_in[12];
  const float* b_hh1 = (const float*)d_in[13];
  const float* out_w = (const float*)d_in[14];
  const float* out_b = (const float*)d_in[15];
  float* out = (float*)d_out;

  float* ws = (float*)d_ws;
  size_t off = 0;
  auto alloc = [&](size_t n) { size_t o = off; off += (n + 63) & ~(size_t)63; return o; };
  float* barf   = ws + alloc(64);                     // bcnt[64]
  float* st     = ws + alloc(4 * BB * HH);
  float* psi_wT = ws + alloc(HH * HH);
  float* phi_wT = ws + alloc(HH * HH);
  float* Mt     = ws + alloc(HH * HH);
  float* wc0T   = ws + alloc(HH * GG);
  float* Bm     = ws + alloc(HH * GG);
  float* whh0T  = ws + alloc(HH * GG);
  float* wih1T  = ws + alloc(HH * GG);
  float* whh1T  = ws + alloc(HH * GG);
  float* wyT    = ws + alloc((size_t)VV * GG);
  float* out_wT = ws + alloc((size_t)HH * 1024);
  float* biasq  = ws + alloc(HH);
  float* pb     = ws + alloc(GG);
  float* zeros  = ws + alloc(GG);
  float* s0 = st, *cs0 = st + BB * HH, *s1 = st + 2 * BB * HH, *cs1 = st + 3 * BB * HH;
  float* cbuf   = ws + alloc(BB * HH);
  float* g0part = ws + alloc((size_t)8 * BB * GG);
  float* g1part = ws + alloc((size_t)8 * BB * GG);
  float* partm  = ws + alloc(BB * 8);
  float* partl  = ws + alloc(BB * 8);
  float* partacc= ws + alloc((size_t)BB * 8 * HH);
  float* s_seq  = ws + alloc((size_t)BB * TT * HH);

  int* bcnt = (int*)barf;

  // zero gating counters + recurrent states (contiguous) every call; zero-bias vector
  hipMemsetAsync(barf, 0, (64 + (size_t)4 * BB * HH) * sizeof(float), stream);
  hipMemsetAsync(zeros, 0, GG * sizeof(float), stream);

  dim3 tb(256);
  transpose_k<<<dim3(16, 16), tb, 0, stream>>>(psi_w, psi_wT, 512, 512, 512, 512, 0);
  transpose_k<<<dim3(16, 16), tb, 0, stream>>>(phi_w, phi_wT, 512, 512, 512, 512, 0);
  transpose_k<<<dim3(16, 64), tb, 0, stream>>>(w_ih0, wc0T, 2048, 2048, 512, 1512, 1000);
  transpose_k<<<dim3(16, 64), tb, 0, stream>>>(w_hh0, whh0T, 2048, 2048, 512, 512, 0);
  transpose_k<<<dim3(16, 64), tb, 0, stream>>>(w_ih1, wih1T, 2048, 2048, 512, 512, 0);
  transpose_k<<<dim3(16, 64), tb, 0, stream>>>(w_hh1, whh1T, 2048, 2048, 512, 512, 0);
  transpose_k<<<dim3(32, 64), tb, 0, stream>>>(w_ih0, wyT, 2048, 2048, 1000, 1512, 0);
  transpose_k<<<dim3(16, 32), tb, 0, stream>>>(out_w, out_wT, 1000, 1024, 512, 512, 0);

  // Mt = phi_w^T @ psi_w ; Bm = psi_wT @ wc0T ; bias folds (psi eliminated from loop)
  biggemm_k<<<dim3(4, 4), tb, 0, stream>>>(phi_wT, psi_w, 512, zeros, Mt, 512, 512);
  biggemm_k<<<dim3(4, 16), tb, 0, stream>>>(psi_wT, wc0T, 2048, zeros, Bm, 2048, 2048);
  biasq_k<<<dim3(2), tb, 0, stream>>>(psi_w, phi_b, biasq);
  pb_k<<<dim3(8), tb, 0, stream>>>(psi_b, wc0T, pb);

  for (int t = 0; t < TT; t++) {
    step1_k<<<dim3(768), tb, 0, stream>>>(h, Mt, biasq, whh0T, whh1T, s0, s1,
                                          g0part, g1part, partm, partl, partacc,
                                          cbuf, bcnt, t);
    gemmB_k<<<dim3(128), tb, 0, stream>>>(cbuf, Bm, g0part);
    act0_k<<<dim3(128), tb, 0, stream>>>(g0part, b_ih0, b_hh0, pb, wyT, y, t, s0, cs0);
    gemmI_k<<<dim3(128), tb, 0, stream>>>(s0, wih1T, g1part);
    act1_k<<<dim3(128), tb, 0, stream>>>(g1part, b_ih1, b_hh1, t, s1, cs1, s_seq);
  }

  // out = s_seq @ out_w.T + out_b   [12800, 1000]
  biggemm_k<<<dim3(100, 8), tb, 0, stream>>>(s_seq, out_wT, 1024, out_b, out, 1000, 1000);
}

// Round 12
// 14171.988 us; speedup vs baseline: 4.1526x; 1.1806x over previous
//
#include <hip/hip_runtime.h>
#include <math.h>

#define BB 64
#define RR 1024
#define TT 200
#define HH 512
#define VV 1000
#define GG 2048

typedef float vf4 __attribute__((ext_vector_type(4)));

__device__ __forceinline__ float sigmf(float x) { return 1.f / (1.f + __expf(-x)); }

// coherent scalar access (agent scope): cross-block data within one kernel (R5-proven)
__device__ __forceinline__ void cstore(float* p, float v) {
  __hip_atomic_store(p, v, __ATOMIC_RELAXED, __HIP_MEMORY_SCOPE_AGENT);
}
__device__ __forceinline__ float cload(const float* p) {
  return __hip_atomic_load(p, __ATOMIC_RELAXED, __HIP_MEMORY_SCOPE_AGENT);
}
__device__ __forceinline__ int armw(int* p, int v) {
  return __hip_atomic_fetch_add(p, v, __ATOMIC_RELAXED, __HIP_MEMORY_SCOPE_AGENT);
}

// ---------------- transpose: dst[n][m] = src[m*sstride + soff + n] ----------------
__global__ __launch_bounds__(256) void transpose_k(const float* __restrict__ src,
    float* __restrict__ dst, int Msrc, int Mdst, int N, int sstride, int soff) {
  __shared__ float tile[32][33];
  int mt = blockIdx.y * 32, ntb = blockIdx.x * 32;
  int tx = threadIdx.x & 31, ty = threadIdx.x >> 5;
  #pragma unroll
  for (int i = ty; i < 32; i += 8) {
    int m = mt + i, n = ntb + tx;
    tile[i][tx] = (m < Msrc && n < N) ? src[(size_t)m * sstride + soff + n] : 0.f;
  }
  __syncthreads();
  #pragma unroll
  for (int i = ty; i < 32; i += 8) {
    int n = ntb + i, m = mt + tx;
    if (n < N && m < Mdst) dst[(size_t)n * Mdst + m] = tile[tx][i];
  }
}

// ---------------- big GEMM: C[M][cld] = A[M][512] @ W[512][wld-slab] + bias ----------------
__global__ __launch_bounds__(256) void biggemm_k(const float* __restrict__ A,
    const float* __restrict__ W, int wld, const float* __restrict__ bias,
    float* __restrict__ C, int cld, int Nout) {
  int mt = blockIdx.x * 128, ntile = blockIdx.y * 128;
  __shared__ float As[16][132];
  __shared__ float Ws[16][132];
  int tid = threadIdx.x;
  int ty = tid >> 4, tx = tid & 15;
  float acc[8][8] = {};
  for (int k0 = 0; k0 < 512; k0 += 16) {
    {
      int row = tid >> 1, kc = (tid & 1) * 8;
      float4 a0 = *(const float4*)&A[(size_t)(mt + row) * 512 + k0 + kc];
      float4 a1 = *(const float4*)&A[(size_t)(mt + row) * 512 + k0 + kc + 4];
      As[kc + 0][row] = a0.x; As[kc + 1][row] = a0.y; As[kc + 2][row] = a0.z; As[kc + 3][row] = a0.w;
      As[kc + 4][row] = a1.x; As[kc + 5][row] = a1.y; As[kc + 6][row] = a1.z; As[kc + 7][row] = a1.w;
      int krow = tid >> 4, nc = (tid & 15) * 8;
      *(float4*)&Ws[krow][nc]     = *(const float4*)&W[(size_t)(k0 + krow) * wld + ntile + nc];
      *(float4*)&Ws[krow][nc + 4] = *(const float4*)&W[(size_t)(k0 + krow) * wld + ntile + nc + 4];
    }
    __syncthreads();
    #pragma unroll
    for (int kk = 0; kk < 16; kk++) {
      float4 a0 = *(float4*)&As[kk][ty * 8];
      float4 a1 = *(float4*)&As[kk][ty * 8 + 4];
      float4 w0 = *(float4*)&Ws[kk][tx * 8];
      float4 w1 = *(float4*)&Ws[kk][tx * 8 + 4];
      float av[8] = {a0.x, a0.y, a0.z, a0.w, a1.x, a1.y, a1.z, a1.w};
      float wv[8] = {w0.x, w0.y, w0.z, w0.w, w1.x, w1.y, w1.z, w1.w};
      #pragma unroll
      for (int i = 0; i < 8; i++)
        #pragma unroll
        for (int j = 0; j < 8; j++)
          acc[i][j] += av[i] * wv[j];
    }
    __syncthreads();
  }
  #pragma unroll
  for (int i = 0; i < 8; i++) {
    int m = mt + ty * 8 + i;
    #pragma unroll
    for (int j = 0; j < 8; j++) {
      int n = ntile + tx * 8 + j;
      if (n < Nout) C[(size_t)m * cld + n] = acc[i][j] + bias[n];
    }
  }
}

// ---------------- tiny setup kernels ----------------
__global__ __launch_bounds__(256) void biasq_k(const float* __restrict__ psi_w,
    const float* __restrict__ phi_b, float* __restrict__ biasq) {
  int i = blockIdx.x * 256 + threadIdx.x;
  float v = 0.f;
  for (int k = 0; k < 512; k++) v += psi_w[(size_t)k * 512 + i] * phi_b[k];
  biasq[i] = v;
}
__global__ __launch_bounds__(256) void pb_k(const float* __restrict__ psi_b,
    const float* __restrict__ wc0T, float* __restrict__ pb) {
  int n = blockIdx.x * 256 + threadIdx.x;
  float v = 0.f;
  for (int k = 0; k < 512; k++) v += psi_b[k] * wc0T[(size_t)k * 2048 + n];
  pb[n] = v;
}

// ---------------- shared 64x64 K=128 GEMM tile (R5-proven) ----------------
struct SmGemm { float Ask[64][68]; float Wsk[64][68]; };
struct SmAttn { float qs[HH]; float wacc[4][HH]; float wml[8]; };

__device__ __forceinline__ void sgemm_tile(const float* A, const float* W, int wld, int k0,
                                           float* Cout, int N, int nt, SmGemm* sm) {
  int tid = threadIdx.x;
  int b0 = (tid >> 4) * 4, n0 = (tid & 15) * 4;
  float acc[4][4] = {};
  for (int kb = 0; kb < 128; kb += 64) {
    {
      int brow = tid & 63;
      int kcb = (tid >> 6) * 16;
      const float* ap = A + (size_t)brow * 512 + k0 + kb + kcb;
      #pragma unroll
      for (int j = 0; j < 4; j++) {
        float4 a4 = *(const float4*)(ap + j * 4);
        sm->Ask[kcb + j * 4 + 0][brow] = a4.x;
        sm->Ask[kcb + j * 4 + 1][brow] = a4.y;
        sm->Ask[kcb + j * 4 + 2][brow] = a4.z;
        sm->Ask[kcb + j * 4 + 3][brow] = a4.w;
      }
      int nc = (tid & 15) * 4;
      #pragma unroll
      for (int j = 0; j < 4; j++) {
        int krow = (tid >> 4) + j * 16;
        *(float4*)&sm->Wsk[krow][nc] =
            *(const float4*)&W[(size_t)(k0 + kb + krow) * wld + nt * 64 + nc];
      }
    }
    __syncthreads();
    #pragma unroll
    for (int kk = 0; kk < 64; kk++) {
      float4 a = *(float4*)&sm->Ask[kk][b0];
      float4 w = *(float4*)&sm->Wsk[kk][n0];
      acc[0][0] += a.x * w.x; acc[0][1] += a.x * w.y; acc[0][2] += a.x * w.z; acc[0][3] += a.x * w.w;
      acc[1][0] += a.y * w.x; acc[1][1] += a.y * w.y; acc[1][2] += a.y * w.z; acc[1][3] += a.y * w.w;
      acc[2][0] += a.z * w.x; acc[2][1] += a.z * w.y; acc[2][2] += a.z * w.z; acc[2][3] += a.z * w.w;
      acc[3][0] += a.w * w.x; acc[3][1] += a.w * w.y; acc[3][2] += a.w * w.z; acc[3][3] += a.w * w.w;
    }
    __syncthreads();
  }
  float* C2 = Cout + (size_t)nt * 64;
  #pragma unroll
  for (int i = 0; i < 4; i++) {
    float4 v = make_float4(acc[i][0], acc[i][1], acc[i][2], acc[i][3]);
    *(float4*)&C2[(size_t)(b0 + i) * N + n0] = v;
  }
}

// ================= K1: early GEMMs — q (shared, 32 tiles) + both hidden-state GEMMs =================
// tiles 0-31: s1@Mt -> qpart (nt 0-7, kc 0-3); 32-159: s0@whh0 -> g0part slabs 4-7;
// 160-287: s1@whh1 -> g1part slabs 4-7.
__global__ __launch_bounds__(256) void early_k(
    const float* s0, const float* s1,
    const float* __restrict__ Mt, const float* __restrict__ whh0T,
    const float* __restrict__ whh1T,
    float* qpart, float* g0part, float* g1part) {
  __shared__ __align__(16) SmGemm smg;
  int bid = blockIdx.x;
  if (bid < 32) {
    int nt = bid & 7, kc = bid >> 3;
    sgemm_tile(s1, Mt, 512, kc * 128, qpart + (size_t)kc * BB * 512, 512, nt, &smg);
  } else if (bid < 160) {
    int idx = bid - 32, nt = idx & 31, kc = idx >> 5;
    sgemm_tile(s0, whh0T, GG, kc * 128, g0part + (size_t)(4 + kc) * BB * GG, GG, nt, &smg);
  } else {
    int idx = bid - 160, nt = idx & 31, kc = idx >> 5;
    sgemm_tile(s1, whh1T, GG, kc * 128, g1part + (size_t)(4 + kc) * BB * GG, GG, nt, &smg);
  }
}

// ================= K2: attention (reads qpart) + gated combine =================
// 512 blocks: b=bid>>3, ch=bid&7 (128 rows each, 32/wave, batch-4 online softmax)
__global__ __launch_bounds__(256) void attn_k(
    const float* __restrict__ h, const float* __restrict__ qpart,
    const float* __restrict__ biasq,
    float* partm, float* partl, float* partacc, float* cbuf,
    int* bcnt, int t) {
  __shared__ __align__(16) SmAttn smr;
  SmAttn* sm = &smr;
  int bid = blockIdx.x, tid = threadIdx.x;
  int b = bid >> 3, ch = bid & 7;
  // q[d] = biasq[d] + sum_{p<4} qpart[p][b][d]
  for (int d = tid; d < HH; d += 256) {
    float v = biasq[d];
    #pragma unroll
    for (int p = 0; p < 4; p++) v += qpart[((size_t)p * BB + b) * HH + d];
    sm->qs[d] = v;
  }
  __syncthreads();
  int wave = tid >> 6, lane = tid & 63;
  float qreg[8];
  {
    const float* qp = sm->qs + lane * 8;
    #pragma unroll
    for (int j = 0; j < 8; j++) qreg[j] = qp[j];
  }
  float m = -INFINITY, l = 0.f;
  float acc[8] = {};
  const float* hbase = h + ((size_t)b * RR + ch * 128 + wave * 32) * HH + lane * 8;
  vf4 c[4][2], n[4][2];
  #pragma unroll
  for (int k = 0; k < 4; k++) {
    c[k][0] = *(const vf4*)(hbase + (size_t)k * HH);
    c[k][1] = *(const vf4*)(hbase + (size_t)k * HH + 4);
  }
  for (int bt = 0; bt < 8; bt++) {
    if (bt < 7) {
      #pragma unroll
      for (int k = 0; k < 4; k++) {
        n[k][0] = *(const vf4*)(hbase + (size_t)(bt * 4 + 4 + k) * HH);
        n[k][1] = *(const vf4*)(hbase + (size_t)(bt * 4 + 4 + k) * HH + 4);
      }
    }
    float p[4];
    #pragma unroll
    for (int k = 0; k < 4; k++) {
      vf4 u = c[k][0], v = c[k][1];
      p[k] = qreg[0] * u.x + qreg[1] * u.y + qreg[2] * u.z + qreg[3] * u.w
           + qreg[4] * v.x + qreg[5] * v.y + qreg[6] * v.z + qreg[7] * v.w;
    }
    #pragma unroll
    for (int off = 32; off > 0; off >>= 1) {
      #pragma unroll
      for (int k = 0; k < 4; k++) p[k] += __shfl_xor(p[k], off, 64);
    }
    float bm = fmaxf(fmaxf(p[0], p[1]), fmaxf(p[2], p[3]));
    float mn = fmaxf(m, bm);
    float scl = __expf(m - mn);
    float w0 = __expf(p[0] - mn), w1 = __expf(p[1] - mn);
    float w2 = __expf(p[2] - mn), w3 = __expf(p[3] - mn);
    l = l * scl + w0 + w1 + w2 + w3;
    #pragma unroll
    for (int j = 0; j < 4; j++) {
      acc[j]     = acc[j]     * scl + w0 * c[0][0][j] + w1 * c[1][0][j] + w2 * c[2][0][j] + w3 * c[3][0][j];
      acc[j + 4] = acc[j + 4] * scl + w0 * c[0][1][j] + w1 * c[1][1][j] + w2 * c[2][1][j] + w3 * c[3][1][j];
    }
    m = mn;
    #pragma unroll
    for (int k = 0; k < 4; k++) { c[k][0] = n[k][0]; c[k][1] = n[k][1]; }
  }
  #pragma unroll
  for (int j = 0; j < 8; j++) sm->wacc[wave][lane * 8 + j] = acc[j];
  if (lane == 0) { sm->wml[wave] = m; sm->wml[4 + wave] = l; }
  __syncthreads();
  float M = fmaxf(fmaxf(sm->wml[0], sm->wml[1]), fmaxf(sm->wml[2], sm->wml[3]));
  float e0 = __expf(sm->wml[0] - M), e1 = __expf(sm->wml[1] - M);
  float e2 = __expf(sm->wml[2] - M), e3 = __expf(sm->wml[3] - M);
  if (tid == 0) {
    cstore(&partm[b * 8 + ch], M);
    cstore(&partl[b * 8 + ch], sm->wml[4] * e0 + sm->wml[5] * e1 + sm->wml[6] * e2 + sm->wml[7] * e3);
  }
  for (int d = tid; d < HH; d += 256)
    cstore(&partacc[((size_t)b * 8 + ch) * HH + d],
           sm->wacc[0][d] * e0 + sm->wacc[1][d] * e1 + sm->wacc[2][d] * e2 + sm->wacc[3][d] * e3);
  __syncthreads();                       // all waves' partial stores issued
  __shared__ int cflag;
  if (tid == 0) { __threadfence(); cflag = armw(&bcnt[b], 1); }
  __syncthreads();
  if (cflag == 8 * t + 7) {              // 8th finisher for b combines (order-independent)
    float Mx = -INFINITY;
    #pragma unroll
    for (int p = 0; p < 8; p++) Mx = fmaxf(Mx, cload(&partm[b * 8 + p]));
    float sc2[8]; float L = 0.f;
    #pragma unroll
    for (int p = 0; p < 8; p++) {
      sc2[p] = __expf(cload(&partm[b * 8 + p]) - Mx);
      L += sc2[p] * cload(&partl[b * 8 + p]);
    }
    float inv = 1.f / L;
    for (int d = tid; d < HH; d += 256) {
      float v = 0.f;
      #pragma unroll
      for (int p = 0; p < 8; p++) v += sc2[p] * cload(&partacc[((size_t)b * 8 + p) * HH + d]);
      cbuf[b * HH + d] = v * inv;        // consumed next kernel
    }
  }
}

// ================= K3 / K5: single 64x64-tile GEMM kernels =================
__global__ __launch_bounds__(256) void gemmB_k(const float* __restrict__ cbuf,
    const float* __restrict__ Bm, float* g0part) {
  __shared__ __align__(16) SmGemm smg;
  int nt = blockIdx.x & 31, kc = blockIdx.x >> 5;
  sgemm_tile(cbuf, Bm, GG, kc * 128, g0part + (size_t)kc * BB * GG, GG, nt, &smg);
}
__global__ __launch_bounds__(256) void gemmI_k(const float* __restrict__ s0,
    const float* __restrict__ wih1T, float* g1part) {
  __shared__ __align__(16) SmGemm smg;
  int nt = blockIdx.x & 31, kc = blockIdx.x >> 5;
  sgemm_tile(s0, wih1T, GG, kc * 128, g1part + (size_t)kc * BB * GG, GG, nt, &smg);
}

// ================= K4: act0 ; K6: act1 =================
__global__ __launch_bounds__(256) void act0_k(const float* __restrict__ gpart,
    const float* __restrict__ b_ih, const float* __restrict__ b_hh,
    const float* __restrict__ pb, const float* __restrict__ wyT,
    const int* __restrict__ y, int t,
    float* __restrict__ s0, float* __restrict__ cs0) {
  int idx = blockIdx.x * 256 + threadIdx.x;
  int b = idx >> 9, jj = idx & 511;
  int yv = y[b * TT + t];
  float g[4];
  #pragma unroll
  for (int gi = 0; gi < 4; gi++) {
    int j = gi * 512 + jj;
    float v = b_ih[j] + b_hh[j] + pb[j] + wyT[(size_t)yv * GG + j];
    #pragma unroll
    for (int p = 0; p < 8; p++) v += gpart[((size_t)p * BB + b) * GG + j];
    g[gi] = v;
  }
  float cn = sigmf(g[1]) * cs0[idx] + sigmf(g[0]) * tanhf(g[2]);
  cs0[idx] = cn;
  s0[idx] = sigmf(g[3]) * tanhf(cn);
}

__global__ __launch_bounds__(256) void act1_k(const float* __restrict__ gpart,
    const float* __restrict__ b_ih, const float* __restrict__ b_hh,
    int t, float* __restrict__ s1, float* __restrict__ cs1, float* __restrict__ s_seq) {
  int idx = blockIdx.x * 256 + threadIdx.x;
  int b = idx >> 9, jj = idx & 511;
  float g[4];
  #pragma unroll
  for (int gi = 0; gi < 4; gi++) {
    int j = gi * 512 + jj;
    float v = b_ih[j] + b_hh[j];
    #pragma unroll
    for (int p = 0; p < 8; p++) v += gpart[((size_t)p * BB + b) * GG + j];
    g[gi] = v;
  }
  float cn = sigmf(g[1]) * cs1[idx] + sigmf(g[0]) * tanhf(g[2]);
  cs1[idx] = cn;
  float hv = sigmf(g[3]) * tanhf(cn);
  s1[idx] = hv;
  __builtin_nontemporal_store(hv, &s_seq[((size_t)b * TT + t) * HH + jj]);
}

extern "C" void kernel_launch(void* const* d_in, const int* in_sizes, int n_in,
                              void* d_out, int out_size, void* d_ws, size_t ws_size,
                              hipStream_t stream) {
  (void)in_sizes; (void)n_in; (void)out_size; (void)ws_size;
  const float* h     = (const float*)d_in[0];
  const int*   y     = (const int*)d_in[1];
  const float* phi_w = (const float*)d_in[2];
  const float* phi_b = (const float*)d_in[3];
  const float* psi_w = (const float*)d_in[4];
  const float* psi_b = (const float*)d_in[5];
  const float* w_ih0 = (const float*)d_in[6];
  const float* w_hh0 = (const float*)d_in[7];
  const float* b_ih0 = (const float*)d_in[8];
  const float* b_hh0 = (const float*)d_in[9];
  const float* w_ih1 = (const float*)d_in[10];
  const float* w_hh1 = (const float*)d_in[11];
  const float* b_ih1 = (const float*)d_in[12];
  const float* b_hh1 = (const float*)d_in[13];
  const float* out_w = (const float*)d_in[14];
  const float* out_b = (const float*)d_in[15];
  float* out = (float*)d_out;

  float* ws = (float*)d_ws;
  size_t off = 0;
  auto alloc = [&](size_t n) { size_t o = off; off += (n + 63) & ~(size_t)63; return o; };
  float* barf   = ws + alloc(64);                     // bcnt[64]
  float* st     = ws + alloc(4 * BB * HH);
  float* psi_wT = ws + alloc(HH * HH);
  float* phi_wT = ws + alloc(HH * HH);
  float* Mt     = ws + alloc(HH * HH);
  float* wc0T   = ws + alloc(HH * GG);
  float* Bm     = ws + alloc(HH * GG);
  float* whh0T  = ws + alloc(HH * GG);
  float* wih1T  = ws + alloc(HH * GG);
  float* whh1T  = ws + alloc(HH * GG);
  float* wyT    = ws + alloc((size_t)VV * GG);
  float* out_wT = ws + alloc((size_t)HH * 1024);
  float* biasq  = ws + alloc(HH);
  float* pb     = ws + alloc(GG);
  float* zeros  = ws + alloc(GG);
  float* s0 = st, *cs0 = st + BB * HH, *s1 = st + 2 * BB * HH, *cs1 = st + 3 * BB * HH;
  float* qpart  = ws + alloc(4 * BB * HH);
  float* cbuf   = ws + alloc(BB * HH);
  float* g0part = ws + alloc((size_t)8 * BB * GG);
  float* g1part = ws + alloc((size_t)8 * BB * GG);
  float* partm  = ws + alloc(BB * 8);
  float* partl  = ws + alloc(BB * 8);
  float* partacc= ws + alloc((size_t)BB * 8 * HH);
  float* s_seq  = ws + alloc((size_t)BB * TT * HH);

  int* bcnt = (int*)barf;

  // zero gating counters + recurrent states (contiguous) every call; zero-bias vector
  hipMemsetAsync(barf, 0, (64 + (size_t)4 * BB * HH) * sizeof(float), stream);
  hipMemsetAsync(zeros, 0, GG * sizeof(float), stream);

  dim3 tb(256);
  transpose_k<<<dim3(16, 16), tb, 0, stream>>>(psi_w, psi_wT, 512, 512, 512, 512, 0);
  transpose_k<<<dim3(16, 16), tb, 0, stream>>>(phi_w, phi_wT, 512, 512, 512, 512, 0);
  transpose_k<<<dim3(16, 64), tb, 0, stream>>>(w_ih0, wc0T, 2048, 2048, 512, 1512, 1000);
  transpose_k<<<dim3(16, 64), tb, 0, stream>>>(w_hh0, whh0T, 2048, 2048, 512, 512, 0);
  transpose_k<<<dim3(16, 64), tb, 0, stream>>>(w_ih1, wih1T, 2048, 2048, 512, 512, 0);
  transpose_k<<<dim3(16, 64), tb, 0, stream>>>(w_hh1, whh1T, 2048, 2048, 512, 512, 0);
  transpose_k<<<dim3(32, 64), tb, 0, stream>>>(w_ih0, wyT, 2048, 2048, 1000, 1512, 0);
  transpose_k<<<dim3(16, 32), tb, 0, stream>>>(out_w, out_wT, 1000, 1024, 512, 512, 0);

  // Mt = phi_w^T @ psi_w ; Bm = psi_wT @ wc0T ; bias folds (psi eliminated from loop)
  biggemm_k<<<dim3(4, 4), tb, 0, stream>>>(phi_wT, psi_w, 512, zeros, Mt, 512, 512);
  biggemm_k<<<dim3(4, 16), tb, 0, stream>>>(psi_wT, wc0T, 2048, zeros, Bm, 2048, 2048);
  biasq_k<<<dim3(2), tb, 0, stream>>>(psi_w, phi_b, biasq);
  pb_k<<<dim3(8), tb, 0, stream>>>(psi_b, wc0T, pb);

  for (int t = 0; t < TT; t++) {
    early_k<<<dim3(288), tb, 0, stream>>>(s0, s1, Mt, whh0T, whh1T,
                                          qpart, g0part, g1part);
    attn_k<<<dim3(512), tb, 0, stream>>>(h, qpart, biasq,
                                         partm, partl, partacc, cbuf, bcnt, t);
    gemmB_k<<<dim3(128), tb, 0, stream>>>(cbuf, Bm, g0part);
    act0_k<<<dim3(128), tb, 0, stream>>>(g0part, b_ih0, b_hh0, pb, wyT, y, t, s0, cs0);
    gemmI_k<<<dim3(128), tb, 0, stream>>>(s0, wih1T, g1part);
    act1_k<<<dim3(128), tb, 0, stream>>>(g1part, b_ih1, b_hh1, t, s1, cs1, s_seq);
  }

  // out = s_seq @ out_w.T + out_b   [12800, 1000]
  biggemm_k<<<dim3(100, 8), tb, 0, stream>>>(s_seq, out_wT, 1024, out_b, out, 1000, 1000);
}